// Round 8
// baseline (106.403 us; speedup 1.0000x reference)
//
#include <hip/hip_runtime.h>

// Updater: B=4194304 sequential scan, 3 independent scalar recurrences
//   net' = sigmoid(10*(net + u - 0.5)), u = W*x + b, pred = x . net'
// Chunked-scan parallelization with certified warm-up (monotone map ->
// trajectories from 0 and 1 bracket the truth; dual-trajectory warm-up with
// wave-uniform early exit; geometric global backoff, rare, exact at net0).
//
// R8 vs R7 (~27.6us kernel, zero delta from serial-phase removals).
// Re-fitted model: four different memory structures all land 27-31us ->
// memory layout is not the bottleneck. The untouched term: BACKOFF
// FREQUENCY. The map is expansive near n+u=0.5 (sigma' up to 2.5), bracket
// shrink is stochastic; if P(lane unconverged in 32) ~ 1%, then
// P(wave fails __all) ~ 47% -> ~half the waves run the 128-step global
// backoff (~7.5us serial straggler each). Fix: WARM=64 in the fast path.
//  - At CHUNK=32 the 64-step warm window is exactly lanes t-2,t-1's chunks:
//    s<32 pulls fx from lane-2 (a2), s>=32 from lane-1 (a1). Only lanes
//    0,1 read the per-wave boundary buffer (now 64 entries, 4KB total).
//  - Extra 32 warm steps are mostly post-convergence single steps
//    (~78cy vs 138cy dual) -> +1.5-2us issue; backoff probability ~p^2
//    -> straggler tail deleted. Backoff starts at 256 steps.
//  - block0/wave0 back on the rolled smin-predicated global path (R7
//    proved this one-wave path costs ~0; needed since lane1's window is
//    half-invalid at WARM=64).

#if __has_builtin(__builtin_amdgcn_exp2f)
#define EXP2F(v) __builtin_amdgcn_exp2f(v)
#else
#define EXP2F(v) __expf(0.6931471805599453f * (v))
#endif

namespace {
constexpr int   BTOT   = 4194304;
constexpr int   CHUNK  = 32;                  // output steps per thread
constexpr int   BLOCK  = 256;
constexpr int   BSTEPS = BLOCK * CHUNK;       // 8192 steps per block
constexpr int   WARM   = 64;                  // warm-up window (steps)
constexpr int   GRID   = BTOT / BSTEPS;       // 512 blocks
constexpr float KEXP   = -14.426950408889634f; // -10 * log2(e)
constexpr float EPS    = 1e-5f;
}

// sigmoid(10*(n+u-0.5)) = rcp(1 + exp2(KEXP*n + c)), c = (KEXP*W)x + KEXP*(b-.5)
#define CVALS(X0_, X1_, X2_)                                                   \
  const float c0 = fmaf(kw00, (X0_), fmaf(kw01, (X1_), fmaf(kw02, (X2_), kb0))); \
  const float c1 = fmaf(kw10, (X0_), fmaf(kw11, (X1_), fmaf(kw12, (X2_), kb1))); \
  const float c2 = fmaf(kw20, (X0_), fmaf(kw21, (X1_), fmaf(kw22, (X2_), kb2)));

#define SIG(N, C) __builtin_amdgcn_rcpf(1.0f + EXP2F(fmaf(KEXP, (N), (C))))

#define PULL(VAL_, AD_) \
  __int_as_float(__builtin_amdgcn_ds_bpermute((AD_), __float_as_int(VAL_)))

// warm-step S_ (compile-time literal; region branch folds):
//   s<32 : x = lane-2's fx[3s..];   boundary lanes 0,1 -> wbuf[s + 32*lane]
//   s>=32: x = lane-1's fx[3(s-32)..]; boundary lane 0 -> wbuf[s]
#define FETCH1(S_, XD0, XD1, XD2)                                              \
  if ((S_) < 32) {                                                             \
    XD0 = PULL(fx[3 * (S_) + 0], a2);                                          \
    XD1 = PULL(fx[3 * (S_) + 1], a2);                                          \
    XD2 = PULL(fx[3 * (S_) + 2], a2);                                          \
    if (lane < 2) {                                                            \
      const float4 wv_ = wb[(S_) + (lane << 5)];                               \
      XD0 = wv_.x; XD1 = wv_.y; XD2 = wv_.z;                                   \
    }                                                                          \
  } else {                                                                     \
    XD0 = PULL(fx[3 * ((S_) - 32) + 0], a1);                                   \
    XD1 = PULL(fx[3 * ((S_) - 32) + 1], a1);                                   \
    XD2 = PULL(fx[3 * ((S_) - 32) + 2], a1);                                   \
    if (lane < 1) {                                                            \
      const float4 wv_ = wb[(S_)];                                             \
      XD0 = wv_.x; XD1 = wv_.y; XD2 = wv_.z;                                   \
    }                                                                          \
  }

// dual-trajectory (bracket) step
#define DSTEP(X0_, X1_, X2_)                                                   \
  {                                                                            \
    CVALS(X0_, X1_, X2_)                                                       \
    lo0 = SIG(lo0, c0); hi0 = SIG(hi0, c0);                                    \
    lo1 = SIG(lo1, c1); hi1 = SIG(hi1, c1);                                    \
    lo2 = SIG(lo2, c2); hi2 = SIG(hi2, c2);                                    \
  }

// single-trajectory step
#define SSTEP(X0_, X1_, X2_)                                                   \
  {                                                                            \
    CVALS(X0_, X1_, X2_)                                                       \
    m0 = SIG(m0, c0); m1 = SIG(m1, c1); m2 = SIG(m2, c2);                      \
  }

// warm batch: 4 steps; fetches hoisted above the wave-uniform branch
#define WBATCH(B_)                                                             \
  {                                                                            \
    float X00,X01,X02,X10,X11,X12,X20,X21,X22,X30,X31,X32;                     \
    FETCH1(4*(B_)+0, X00, X01, X02)                                            \
    FETCH1(4*(B_)+1, X10, X11, X12)                                            \
    FETCH1(4*(B_)+2, X20, X21, X22)                                            \
    FETCH1(4*(B_)+3, X30, X31, X32)                                            \
    if (!single) {                                                             \
      DSTEP(X00, X01, X02) DSTEP(X10, X11, X12)                                \
      DSTEP(X20, X21, X22) DSTEP(X30, X31, X32)                                \
      conv = ((hi0 - lo0) < EPS) & ((hi1 - lo1) < EPS) & ((hi2 - lo2) < EPS);  \
      if (__all(conv)) {                                                       \
        m0 = 0.5f * (lo0 + hi0); m1 = 0.5f * (lo1 + hi1);                      \
        m2 = 0.5f * (lo2 + hi2);                                               \
        single = true;                                                         \
      }                                                                        \
    } else {                                                                   \
      SSTEP(X00, X01, X02) SSTEP(X10, X11, X12)                                \
      SSTEP(X20, X21, X22) SSTEP(X30, X31, X32)                                \
    }                                                                          \
  }

// main step: advance + pred (x from registers)
#define MS(P_, X0_, X1_, X2_)                                                  \
  {                                                                            \
    CVALS(X0_, X1_, X2_)                                                       \
    m0 = SIG(m0, c0); m1 = SIG(m1, c1); m2 = SIG(m2, c2);                      \
    P_ = fmaf((X0_), m0, fmaf((X1_), m1, (X2_) * m2));                         \
  }

__global__ __launch_bounds__(BLOCK, 2) void Updater_65395172049297_kernel(
    const float* __restrict__ x, const float* __restrict__ W,
    const float* __restrict__ bv, const float* __restrict__ n0v,
    float* __restrict__ out)
{
    __shared__ float4 wbuf[BLOCK / 64][WARM];   // 4 waves x 64 steps = 4KB

    const float kw00 = KEXP * W[0], kw01 = KEXP * W[1], kw02 = KEXP * W[2];
    const float kw10 = KEXP * W[3], kw11 = KEXP * W[4], kw12 = KEXP * W[5];
    const float kw20 = KEXP * W[6], kw21 = KEXP * W[7], kw22 = KEXP * W[8];
    const float kb0 = KEXP * (bv[0] - 0.5f);
    const float kb1 = KEXP * (bv[1] - 0.5f);
    const float kb2 = KEXP * (bv[2] - 0.5f);
    const float n00 = n0v[0], n01 = n0v[1], n02 = n0v[2];

    const int  lane  = threadIdx.x & 63;
    const int  w     = threadIdx.x >> 6;
    const long S     = (long)blockIdx.x * BSTEPS;
    const long start = S + (long)threadIdx.x * CHUNK;
    const int  a1    = ((lane >= 1) ? (lane - 1) : 0) << 2;
    const int  a2    = ((lane >= 2) ? (lane - 2) : 0) << 2;
    const float4* wb = wbuf[w];

    // ---- per-wave boundary window load FIRST (1 load/lane, all 64) ----
    float4 wv;
    {
        const long wbase = S + (long)w * (64 * CHUNK);
        long sstep = wbase - WARM + lane;
        if (sstep < 0) sstep = 0;   // block0/wave0 only; that wave uses the
                                    // rolled special path, not wbuf
        const float* xp = x + 3 * sstep;
        wv = make_float4(xp[0], xp[1], xp[2], 0.0f);
    }

    // ---- one-shot gather: this thread's 32-step x chunk into registers ----
    float fx[96];
    {
        const float4* mp = reinterpret_cast<const float4*>(x + 3 * start);
#pragma unroll
        for (int i = 0; i < 24; ++i) {
            const float4 v = mp[i];
            fx[4 * i + 0] = v.x; fx[4 * i + 1] = v.y;
            fx[4 * i + 2] = v.z; fx[4 * i + 3] = v.w;
        }
    }

    // wave-private LDS write; no __syncthreads needed (same-wave lockstep)
    wbuf[w][lane] = wv;

    const bool exact   = (start <= (long)WARM);   // block0/wave0 lanes 0,1,2
    const int  smin    = exact ? (int)(WARM - (int)start) : 0;
    const bool special = (blockIdx.x == 0) && (w == 0);

    float lo0, lo1, lo2, hi0, hi1, hi2;
    if (exact) { lo0 = hi0 = n00; lo1 = hi1 = n01; lo2 = hi2 = n02; }
    else       { lo0 = lo1 = lo2 = 0.0f; hi0 = hi1 = hi2 = 1.0f; }

    bool  conv = false, single = false;
    float m0 = n00, m1 = n01, m2 = n02;

    if (special) {
        // ONE wave in the grid: rolled warm-up straight from global x.
        // Exact lanes skip s<smin (seeded at net0 -> exact trajectory).
        for (int s = 0; s < WARM; ++s) {
            if (s >= smin) {
                const long as_ = start - WARM + s;   // >= 0 when s >= smin
                const float X0 = x[3 * as_], X1 = x[3 * as_ + 1], X2 = x[3 * as_ + 2];
                DSTEP(X0, X1, X2)
            }
        }
        conv = ((hi0 - lo0) < EPS) & ((hi1 - lo1) < EPS) & ((hi2 - lo2) < EPS);
        if (__all(conv)) {
            m0 = 0.5f * (lo0 + hi0); m1 = 0.5f * (lo1 + hi1); m2 = 0.5f * (lo2 + hi2);
            single = true;
        }
    } else {
        WBATCH(0)  WBATCH(1)  WBATCH(2)  WBATCH(3)
        WBATCH(4)  WBATCH(5)  WBATCH(6)  WBATCH(7)
        WBATCH(8)  WBATCH(9)  WBATCH(10) WBATCH(11)
        WBATCH(12) WBATCH(13) WBATCH(14) WBATCH(15)
    }

    if (!single) {
        // rare certified backoff: extend window 4x per attempt (global x)
        for (int at = 1; at < 10 && !conv; ++at) {
            long wl2 = (long)WARM << (2 * at);
            long bgn = start - wl2;
            bool ex2 = (bgn <= 0);
            if (ex2) bgn = 0;
            if (ex2) { lo0 = hi0 = n00; lo1 = hi1 = n01; lo2 = hi2 = n02; }
            else     { lo0 = lo1 = lo2 = 0.0f; hi0 = hi1 = hi2 = 1.0f; }
            const float4* bp = reinterpret_cast<const float4*>(x + 3 * bgn);
            const long ng = (start - bgn) >> 2;   // groups of 4 steps
            for (long q = 0; q < ng; ++q) {
                const float4 A4 = bp[3 * q], B4 = bp[3 * q + 1], C4 = bp[3 * q + 2];
                DSTEP(A4.x, A4.y, A4.z)
                DSTEP(A4.w, B4.x, B4.y)
                DSTEP(B4.z, B4.w, C4.x)
                DSTEP(C4.y, C4.z, C4.w)
            }
            conv = ex2 || (((hi0 - lo0) < EPS) & ((hi1 - lo1) < EPS) &
                           ((hi2 - lo2) < EPS));
        }
        m0 = 0.5f * (lo0 + hi0); m1 = 0.5f * (lo1 + hi1); m2 = 0.5f * (lo2 + hi2);
    }

    // ---- main chunk: 32 steps from registers, 8 float4 stores ----
    float4* op = reinterpret_cast<float4*>(out + start);
#pragma unroll
    for (int q = 0; q < 8; ++q) {
        float p0, p1, p2, p3;
        MS(p0, fx[12 * q + 0], fx[12 * q + 1],  fx[12 * q + 2]);
        MS(p1, fx[12 * q + 3], fx[12 * q + 4],  fx[12 * q + 5]);
        MS(p2, fx[12 * q + 6], fx[12 * q + 7],  fx[12 * q + 8]);
        MS(p3, fx[12 * q + 9], fx[12 * q + 10], fx[12 * q + 11]);
        op[q] = make_float4(p0, p1, p2, p3);
    }
}

extern "C" void kernel_launch(void* const* d_in, const int* in_sizes, int n_in,
                              void* d_out, int out_size, void* d_ws, size_t ws_size,
                              hipStream_t stream) {
    const float* x   = (const float*)d_in[0];   // (B,1,3)
    const float* W   = (const float*)d_in[1];   // (3,3)
    const float* bv  = (const float*)d_in[2];   // (3,)
    const float* n0v = (const float*)d_in[3];   // (3,1)
    float*       out = (float*)d_out;           // (B,1)
    Updater_65395172049297_kernel<<<GRID, BLOCK, 0, stream>>>(x, W, bv, n0v, out);
}